// Round 16
// baseline (183.378 us; speedup 1.0000x reference)
//
#include <hip/hip_runtime.h>

#define K_DIM 4096
#define N_DIM 8192
#define PREFIX 1024             // prefix columns for the underflow test
#define TAILC (N_DIM - PREFIX)  // 7168 tail columns
#define PCB 256                 // prefix-colsum blocks (16 rows each)
#define MFB (K_DIM / 2)         // mainfill blocks (2048; 2 rows each)

typedef float f32x4 __attribute__((ext_vector_type(4)));
typedef int   i32x4 __attribute__((ext_vector_type(4)));
typedef unsigned int u32x4 __attribute__((ext_vector_type(4)));

// ws layout:
// done[64] (uint; zeroed by prep each launch)
// partial0 [PCB*PREFIX] (1 MB)
// prior_eps[N], dope[N], Tprod[PREFIX], colsum_new[N]
// flag[64], counter[64], worklist[K], nzp[PCB]  (ints)

__device__ __forceinline__ float fast_tanh_half(float h) {
    // tanh(h/2) = 1 - 2/(e^h + 1)
    float e = __expf(h);
    float r = __builtin_amdgcn_rcpf(e + 1.0f);
    return __builtin_fmaf(-2.0f, r, 1.0f);
}

// clip(2*atanh(P/t), -1, 1) for t != 0, else 0.  2*atanh(P/t)=ln((t+P)/(t-P))
__device__ __forceinline__ float check_msg(float t, float P) {
    float q = (t + P) * __builtin_amdgcn_rcpf(t - P);
    float m = 0.69314718055994531f * __log2f(q);
    m = fminf(fmaxf(m, -1.0f), 1.0f);
    return (t == 0.0f) ? 0.0f : m;
}

// D1: column sums of Hxs[:, 0:PREFIX] + nonzero detect. grid=PCB x 256.
__global__ __launch_bounds__(256) void prefix_colsum_kernel(const float* __restrict__ Hxs,
                                                            float* __restrict__ partial0,
                                                            int* __restrict__ nzp) {
    const int t = threadIdx.x;
    const int b = blockIdx.x;
    const f32x4* p = reinterpret_cast<const f32x4*>(Hxs + (size_t)b * 16 * N_DIM);
    f32x4 acc = {0.f, 0.f, 0.f, 0.f};
    unsigned nz = 0u;
    #pragma unroll
    for (int r = 0; r < 16; ++r) {
        f32x4 v = __builtin_nontemporal_load(&p[(size_t)r * (N_DIM / 4) + t]);
        acc.x += v.x; acc.y += v.y; acc.z += v.z; acc.w += v.w;
        u32x4 u;
        __builtin_memcpy(&u, &v, 16);
        nz |= (u.x | u.y | u.z | u.w);
    }
    reinterpret_cast<f32x4*>(partial0 + (size_t)b * PREFIX)[t] = acc;
    __shared__ int snz;
    if (t == 0) snz = 0;
    __syncthreads();
    if (__any(nz != 0u ? 1 : 0)) {
        if ((t & 63) == 0) atomicOr(&snz, 1);
    }
    __syncthreads();
    if (t == 0) nzp[b] = snz;
}

// D2: prep. grid = 32 x 256 (thread per column n).
// dope all N; colsum_new=0; optimistic Mout = f(dope) (exact on fast path);
// n<PREFIX: prior_eps + Tprod. Block 0: flag, counter, done := 0.
__global__ __launch_bounds__(256) void prep_kernel(const float* __restrict__ ps,
                                                   const float* __restrict__ Min,
                                                   const float* __restrict__ partial0,
                                                   const int* __restrict__ nzp,
                                                   float* __restrict__ prior_eps,
                                                   float* __restrict__ dope_out,
                                                   float* __restrict__ Tprod,
                                                   float* __restrict__ colsum_new,
                                                   float* __restrict__ Mout,
                                                   int* __restrict__ flag,
                                                   int* __restrict__ counter,
                                                   unsigned* __restrict__ done) {
    const int t = threadIdx.x;
    const int n = blockIdx.x * 256 + t;

    float p0 = ps[2 * n], p1 = ps[2 * n + 1];
    float p1n = p1 / (p0 + p1);
    float dp = logf(1.0f - p1n) - logf(p1n);
    dope_out[n] = dp;
    colsum_new[n] = 0.0f;

    // Optimistic output beliefs (colsum_new == 0); last block rewrites on slow path.
    {
        float z = (1.0f - tanhf(dp * 0.5f)) * 0.5f;
        float2 m; m.x = 1.0f - z; m.y = z;
        reinterpret_cast<float2*>(Mout)[n] = m;
    }

    if (blockIdx.x == 0) {
        __shared__ int w[4];
        int v = nzp[t];                                 // PCB = 256 entries
        int any = __any(v != 0 ? 1 : 0) ? 1 : 0;
        if ((t & 63) == 0) w[t >> 6] = any;
        __syncthreads();
        if (t == 0) { flag[0] = (w[0] | w[1] | w[2] | w[3]); counter[0] = 0; }
        if (t < 64) done[t] = 0u;                       // reset last-block counter
    }

    if (n < PREFIX) {
        float cs = 0.0f;
        #pragma unroll 8
        for (int i = 0; i < PCB; ++i)
            cs += partial0[(size_t)i * PREFIX + n];
        float m0 = Min[2 * n], m1 = Min[2 * n + 1];
        float m1n = m1 / (m0 + m1);
        float phi = logf(1.0f - m1n) - logf(m1n);
        float prior = dp + phi + cs;
        prior = fminf(fmaxf(prior, -100.0f), 100.0f);
        float pe = prior + 1e-4f;
        prior_eps[n] = pe;
        float T = tanhf(pe * 0.5f);
        Tprod[n] = (T == 0.0f) ? 1.0f : T;
    }
}

// D3: mainfill + last-block slow-path completion.
// grid = MFB (2048) x 256 (8 blocks/CU, full occupancy). Block b: rows 2b,2b+1.
// Per wave: half-row prefix product (2 H-int4 chunks), butterfly; halves
// combine via 4-float LDS + ONE barrier. pp==0 (|t|<=1 monotone underflow,
// the common case) -> plain-store the 16KB half-row of zeros. Else worklist.
// Then each block bumps `done`; the LAST block alone completes the slow path
// (tail colsum+prior, fixup worklist rows, Mout rewrite) -- correctness-grade,
// never executed on this benchmark's fast path (counter==0 -> return).
__global__ __launch_bounds__(256, 8) void mainfill_kernel(const float* __restrict__ Hxs,
                                                          const int* __restrict__ H,
                                                          const int* __restrict__ x,
                                                          const float* __restrict__ Min,
                                                          const float* __restrict__ dope,
                                                          float* __restrict__ prior_eps,
                                                          const float* __restrict__ Tprod,
                                                          const int* __restrict__ flag,
                                                          float* __restrict__ out,
                                                          float* __restrict__ colsum_new,
                                                          float* __restrict__ Mout,
                                                          int* __restrict__ counter,
                                                          int* __restrict__ worklist,
                                                          unsigned* __restrict__ done) {
    const int t = threadIdx.x;
    const int w = t >> 6;                 // 0..3
    const int lane = t & 63;
    const int half = w & 1;
    const int k = blockIdx.x * 2 + (w >> 1);

    const bool fast = (*flag == 0);
    {
        const i32x4* H4  = reinterpret_cast<const i32x4*>(H + (size_t)k * N_DIM);
        const f32x4* TP4 = reinterpret_cast<const f32x4*>(Tprod);
        const f32x4* PE4 = reinterpret_cast<const f32x4*>(prior_eps);
        const f32x4* HX4 = reinterpret_cast<const f32x4*>(Hxs + (size_t)k * N_DIM);

        // ---- half-row prefix product: 2 int4 chunks (512 cols) ----
        float lp0 = 1.f, lp1 = 1.f;
        #pragma unroll
        for (int u = 0; u < 2; ++u) {
            const int idx = half * 128 + u * 64 + lane;     // int4 idx in [0,256)
            const i32x4 hh = H4[idx];
            float f;
            if (fast) {
                const f32x4 tv = TP4[idx];
                float f0 = hh.x ? tv.x : 1.f;
                float f1 = hh.y ? tv.y : 1.f;
                float f2 = hh.z ? tv.z : 1.f;
                float f3 = hh.w ? tv.w : 1.f;
                f = (f0 * f1) * (f2 * f3);
            } else {
                const f32x4 pe = PE4[idx];
                const f32x4 hx = HX4[idx];
                float t0 = fast_tanh_half((hh.x ? pe.x : 0.f) - hx.x);
                float t1 = fast_tanh_half((hh.y ? pe.y : 0.f) - hx.y);
                float t2 = fast_tanh_half((hh.z ? pe.z : 0.f) - hx.z);
                float t3 = fast_tanh_half((hh.w ? pe.w : 0.f) - hx.w);
                t0 = (t0 == 0.f) ? 1.f : t0;
                t1 = (t1 == 0.f) ? 1.f : t1;
                t2 = (t2 == 0.f) ? 1.f : t2;
                t3 = (t3 == 0.f) ? 1.f : t3;
                f = (t0 * t1) * (t2 * t3);
            }
            if (u == 0) lp0 *= f;
            else        lp1 *= f;
        }
        float hp = lp0 * lp1;
        #pragma unroll
        for (int off = 1; off < 64; off <<= 1)
            hp *= __shfl_xor(hp, off);

        __shared__ float sh[4];
        if (lane == 0) sh[w] = hp;
        __syncthreads();
        const float pp = sh[w & 2] * sh[(w & 2) | 1];

        if (pp == 0.0f) {
            // Full product exactly 0 -> whole row exactly 0. Plain-store stream.
            f32x4* orow = reinterpret_cast<f32x4*>(out + (size_t)k * N_DIM);
            const f32x4 z = {0.f, 0.f, 0.f, 0.f};
            #pragma unroll
            for (int s = 0; s < 16; ++s)
                orow[half * 1024 + s * 64 + lane] = z;
        } else if (half == 0 && lane == 0) {
            int i = atomicAdd(counter, 1);
            worklist[i] = k;
        }
    }

    // ---- last-block-done: exactly one block proceeds ----
    __syncthreads();
    __shared__ int lastFlag;
    if (t == 0) {
        __threadfence();
        unsigned old = __hip_atomic_fetch_add(done, 1u, __ATOMIC_ACQ_REL,
                                              __HIP_MEMORY_SCOPE_AGENT);
        lastFlag = (old == (unsigned)(MFB - 1)) ? 1 : 0;
    }
    __syncthreads();
    if (!lastFlag) return;
    __threadfence();

    const int cnt = *counter;
    if (cnt == 0) return;       // fast path: zeros + optimistic Mout stand

    // ============ slow path (general inputs): single block ============
    // Tail colsum + prior_eps for cols PREFIX..N (28 cols/thread).
    for (int j = t; j < TAILC; j += 256) {
        const int n = PREFIX + j;
        float cs = 0.0f;
        for (int r = 0; r < K_DIM; ++r)
            cs += Hxs[(size_t)r * N_DIM + n];
        float m0 = Min[2 * n], m1 = Min[2 * n + 1];
        float m1n = m1 / (m0 + m1);
        float phi = logf(1.0f - m1n) - logf(m1n);
        float prior = dope[n] + phi + cs;
        prior = fminf(fmaxf(prior, -100.0f), 100.0f);
        prior_eps[n] = prior + 1e-4f;
    }
    __syncthreads();

    // Fixup worklist rows (full general path; writes ALL columns).
    {
        const int wv = t >> 6;
        for (int i = wv; i < cnt; i += 4) {
            const int kk = worklist[i];
            const i32x4* H4  = reinterpret_cast<const i32x4*>(H + (size_t)kk * N_DIM);
            const f32x4* PE4 = reinterpret_cast<const f32x4*>(prior_eps);
            const f32x4* HX4 = reinterpret_cast<const f32x4*>(Hxs + (size_t)kk * N_DIM);

            float lp = 1.0f;
            for (int s = 0; s < 32; ++s) {
                const int idx = s * 64 + lane;
                const i32x4 hh = H4[idx];
                const f32x4 pe = PE4[idx];
                const f32x4 hx = HX4[idx];
                float t0 = fast_tanh_half((hh.x ? pe.x : 0.f) - hx.x);
                float t1 = fast_tanh_half((hh.y ? pe.y : 0.f) - hx.y);
                float t2 = fast_tanh_half((hh.z ? pe.z : 0.f) - hx.z);
                float t3 = fast_tanh_half((hh.w ? pe.w : 0.f) - hx.w);
                t0 = (t0 == 0.f) ? 1.f : t0;
                t1 = (t1 == 0.f) ? 1.f : t1;
                t2 = (t2 == 0.f) ? 1.f : t2;
                t3 = (t3 == 0.f) ? 1.f : t3;
                lp *= (t0 * t1) * (t2 * t3);
            }
            #pragma unroll
            for (int off = 1; off < 64; off <<= 1)
                lp *= __shfl_xor(lp, off);

            const float sgn = 1.0f - 2.0f * (float)x[kk];
            const float P = sgn * lp;

            f32x4* orow = reinterpret_cast<f32x4*>(out + (size_t)kk * N_DIM);
            for (int s = 0; s < 32; ++s) {
                const int idx = s * 64 + lane;
                const i32x4 hh = H4[idx];
                const f32x4 pe = PE4[idx];
                const f32x4 hx = HX4[idx];
                float t0 = fast_tanh_half((hh.x ? pe.x : 0.f) - hx.x);
                float t1 = fast_tanh_half((hh.y ? pe.y : 0.f) - hx.y);
                float t2 = fast_tanh_half((hh.z ? pe.z : 0.f) - hx.z);
                float t3 = fast_tanh_half((hh.w ? pe.w : 0.f) - hx.w);
                f32x4 o;
                o.x = check_msg(t0, P);
                o.y = check_msg(t1, P);
                o.z = check_msg(t2, P);
                o.w = check_msg(t3, P);
                orow[idx] = o;
                const int n0 = idx * 4;
                if (o.x != 0.f) atomicAdd(&colsum_new[n0 + 0], o.x);
                if (o.y != 0.f) atomicAdd(&colsum_new[n0 + 1], o.y);
                if (o.z != 0.f) atomicAdd(&colsum_new[n0 + 2], o.z);
                if (o.w != 0.f) atomicAdd(&colsum_new[n0 + 3], o.w);
            }
        }
    }
    __syncthreads();

    // Rewrite Mout with the true colsum_new.
    for (int n = t; n < N_DIM; n += 256) {
        float z = (1.0f - tanhf((colsum_new[n] + dope[n]) * 0.5f)) * 0.5f;
        Mout[2 * n]     = 1.0f - z;
        Mout[2 * n + 1] = z;
    }
}

extern "C" void kernel_launch(void* const* d_in, const int* in_sizes, int n_in,
                              void* d_out, int out_size, void* d_ws, size_t ws_size,
                              hipStream_t stream) {
    (void)in_sizes; (void)n_in; (void)out_size; (void)ws_size;
    const float* ps  = (const float*)d_in[0];
    const float* Min = (const float*)d_in[1];
    const float* Hxs = (const float*)d_in[2];
    const int*   x   = (const int*)d_in[3];
    const int*   H   = (const int*)d_in[4];

    float* out = (float*)d_out;
    float* Mout = out;                       // N*2 floats
    float* Hxs_new = out + 2 * N_DIM;        // K*N floats

    unsigned* done    = (unsigned*)d_ws;                      // 64 uints
    float* partial0   = (float*)d_ws + 64;                    // PCB*PREFIX (1 MB)
    float* prior_eps  = partial0 + (size_t)PCB * PREFIX;      // N
    float* dope       = prior_eps + N_DIM;                    // N
    float* Tprod      = dope + N_DIM;                         // PREFIX
    float* colsum_new = Tprod + PREFIX;                       // N
    int*   flag       = (int*)(colsum_new + N_DIM);
    int*   counter    = flag + 64;
    int*   worklist   = counter + 64;                         // K ints
    int*   nzp        = worklist + K_DIM;                     // PCB ints

    prefix_colsum_kernel<<<PCB, 256, 0, stream>>>(Hxs, partial0, nzp);

    prep_kernel<<<N_DIM / 256, 256, 0, stream>>>(ps, Min, partial0, nzp,
                                                 prior_eps, dope, Tprod,
                                                 colsum_new, Mout, flag,
                                                 counter, done);

    mainfill_kernel<<<MFB, 256, 0, stream>>>(Hxs, H, x, Min, dope, prior_eps,
                                             Tprod, flag, Hxs_new, colsum_new,
                                             Mout, counter, worklist, done);
}

// Round 17
// 33.423 us; speedup vs baseline: 5.4865x; 5.4865x over previous
//
#include <hip/hip_runtime.h>

#define K_DIM 4096
#define N_DIM 8192
#define PREFIX 512              // prefix columns for the underflow test
#define PCB 256                 // nz-scan blocks (16 rows each)
#define MFB (K_DIM / 2)         // mainfill blocks (2048; 2 rows each)
#define TRB 256                 // tailfix blocks (slow path; 1/CU co-resident)

typedef float f32x4 __attribute__((ext_vector_type(4)));
typedef int   i32x4 __attribute__((ext_vector_type(4)));
typedef unsigned int u32x4 __attribute__((ext_vector_type(4)));

// ws layout:
// bar[64] (uint; zeroed by prep each launch; used only on slow path)
// partial1 [TRB*N]  (8 MB, slow path only)
// prior_eps[N], dope[N], Tprod[PREFIX], colsum_new[N]
// flag[64], counter[64], worklist[K], nzp[PCB]  (ints)

__device__ __forceinline__ float fast_tanh_half(float h) {
    // tanh(h/2) = 1 - 2/(e^h + 1)
    float e = __expf(h);
    float r = __builtin_amdgcn_rcpf(e + 1.0f);
    return __builtin_fmaf(-2.0f, r, 1.0f);
}

// clip(2*atanh(P/t), -1, 1) for t != 0, else 0.  2*atanh(P/t)=ln((t+P)/(t-P))
__device__ __forceinline__ float check_msg(float t, float P) {
    float q = (t + P) * __builtin_amdgcn_rcpf(t - P);
    float m = 0.69314718055994531f * __log2f(q);
    m = fminf(fmaxf(m, -1.0f), 1.0f);
    return (t == 0.0f) ? 0.0f : m;
}

// Grid barrier for the SLOW PATH ONLY (never executed on the fast path).
// TRB=256 blocks = 1 block/CU -> co-resident. Correctness-grade, not fast.
__device__ __forceinline__ void grid_barrier(unsigned* bar, int slot, int nblk) {
    __syncthreads();
    if (threadIdx.x == 0) {
        unsigned* cnt = bar + 2 * slot;
        unsigned* gen = bar + 2 * slot + 1;
        __threadfence();
        unsigned g = __hip_atomic_load(gen, __ATOMIC_ACQUIRE, __HIP_MEMORY_SCOPE_AGENT);
        if (__hip_atomic_fetch_add(cnt, 1u, __ATOMIC_ACQ_REL, __HIP_MEMORY_SCOPE_AGENT) == (unsigned)(nblk - 1)) {
            __hip_atomic_fetch_add(gen, 1u, __ATOMIC_RELEASE, __HIP_MEMORY_SCOPE_AGENT);
        } else {
            while (__hip_atomic_load(gen, __ATOMIC_ACQUIRE, __HIP_MEMORY_SCOPE_AGENT) == g)
                __builtin_amdgcn_s_sleep(32);
        }
        __threadfence();
    }
    __syncthreads();
}

// D1: nz-scan of Hxs[:, 0:PREFIX] (8 MB). grid=PCB x 256; block b: 16 rows.
// Per iteration: 2 rows x 128 f32x4 (waves 0,1 -> row a; waves 2,3 -> row b).
__global__ __launch_bounds__(256) void nzscan_kernel(const float* __restrict__ Hxs,
                                                     int* __restrict__ nzp) {
    const int t = threadIdx.x;
    const int b = blockIdx.x;
    const f32x4* p = reinterpret_cast<const f32x4*>(Hxs + (size_t)b * 16 * N_DIM);
    unsigned nz = 0u;
    #pragma unroll
    for (int it = 0; it < 8; ++it) {
        f32x4 v = __builtin_nontemporal_load(
            &p[(size_t)(it * 2 + (t >> 7)) * (N_DIM / 4) + (t & 127)]);
        u32x4 u;
        __builtin_memcpy(&u, &v, 16);
        nz |= (u.x | u.y | u.z | u.w);
    }
    __shared__ int snz;
    if (t == 0) snz = 0;
    __syncthreads();
    if (__any(nz != 0u ? 1 : 0)) {
        if ((t & 63) == 0) atomicOr(&snz, 1);
    }
    __syncthreads();
    if (t == 0) nzp[b] = snz;
}

// D2: prep. grid = 32 x 256 (thread per column n).
// dope all N; colsum_new=0; optimistic Mout=f(dope) (exact on fast path);
// n<PREFIX: prior/Tprod with colsum==0 (valid iff flag==0; only used then).
// Block 0: flag from nzp, counter=0, bar=0.
__global__ __launch_bounds__(256) void prep_kernel(const float* __restrict__ ps,
                                                   const float* __restrict__ Min,
                                                   const int* __restrict__ nzp,
                                                   float* __restrict__ prior_eps,
                                                   float* __restrict__ dope_out,
                                                   float* __restrict__ Tprod,
                                                   float* __restrict__ colsum_new,
                                                   float* __restrict__ Mout,
                                                   int* __restrict__ flag,
                                                   int* __restrict__ counter,
                                                   unsigned* __restrict__ bar) {
    const int t = threadIdx.x;
    const int n = blockIdx.x * 256 + t;

    float p0 = ps[2 * n], p1 = ps[2 * n + 1];
    float p1n = p1 / (p0 + p1);
    float dp = logf(1.0f - p1n) - logf(p1n);
    dope_out[n] = dp;
    colsum_new[n] = 0.0f;

    // Optimistic output beliefs (colsum_new == 0); tailfix rewrites on slow path.
    {
        float z = (1.0f - tanhf(dp * 0.5f)) * 0.5f;
        float2 m; m.x = 1.0f - z; m.y = z;
        reinterpret_cast<float2*>(Mout)[n] = m;
    }

    if (blockIdx.x == 0) {
        __shared__ int w[4];
        int v = nzp[t];                                 // PCB = 256 entries
        int any = __any(v != 0 ? 1 : 0) ? 1 : 0;
        if ((t & 63) == 0) w[t >> 6] = any;
        __syncthreads();
        if (t == 0) { flag[0] = (w[0] | w[1] | w[2] | w[3]); counter[0] = 0; }
        if (t < 64) bar[t] = 0u;                        // reset slow-path barrier
    }

    if (n < PREFIX) {
        // colsum over prefix == 0 on the fast path (flag==0); these values are
        // only consumed when flag==0 (mainfill returns immediately otherwise,
        // and tailfix recomputes all priors from scratch).
        float m0 = Min[2 * n], m1 = Min[2 * n + 1];
        float m1n = m1 / (m0 + m1);
        float phi = logf(1.0f - m1n) - logf(m1n);
        float prior = dp + phi;
        prior = fminf(fmaxf(prior, -100.0f), 100.0f);
        float pe = prior + 1e-4f;
        prior_eps[n] = pe;
        float T = tanhf(pe * 0.5f);
        Tprod[n] = (T == 0.0f) ? 1.0f : T;
    }
}

// D3: mainfill -- FAST PATH ONLY. grid = MFB x 256 (8 blocks/CU).
// flag!=0 -> return (tailfix handles everything). Block b: rows 2b, 2b+1;
// 2 waves/row. Per wave: ONE H-int4 + ONE Tprod load (256 prefix cols),
// product, butterfly; halves combine via 4-float LDS + ONE barrier.
// pp==0 (|t|<=1 monotone underflow, the common case) -> plain-store the
// 16KB half-row of zeros. Else -> worklist for tailfix.
__global__ __launch_bounds__(256, 8) void mainfill_kernel(const int* __restrict__ H,
                                                          const float* __restrict__ Tprod,
                                                          const int* __restrict__ flag,
                                                          float* __restrict__ out,
                                                          int* __restrict__ counter,
                                                          int* __restrict__ worklist) {
    if (*flag != 0) return;               // slow path owns everything

    const int t = threadIdx.x;
    const int w = t >> 6;                 // 0..3
    const int lane = t & 63;
    const int half = w & 1;
    const int k = blockIdx.x * 2 + (w >> 1);

    const i32x4* H4  = reinterpret_cast<const i32x4*>(H + (size_t)k * N_DIM);
    const f32x4* TP4 = reinterpret_cast<const f32x4*>(Tprod);

    // ---- half-row prefix product: 1 int4 chunk (256 cols) ----
    const int idx = half * 64 + lane;     // int4 idx in [0,128)
    const i32x4 hh = H4[idx];
    const f32x4 tv = TP4[idx];
    float f0 = hh.x ? tv.x : 1.f;
    float f1 = hh.y ? tv.y : 1.f;
    float f2 = hh.z ? tv.z : 1.f;
    float f3 = hh.w ? tv.w : 1.f;
    float hp = (f0 * f1) * (f2 * f3);
    #pragma unroll
    for (int off = 1; off < 64; off <<= 1)
        hp *= __shfl_xor(hp, off);

    __shared__ float sh[4];
    if (lane == 0) sh[w] = hp;
    __syncthreads();                      // the only barrier
    const float pp = sh[w & 2] * sh[(w & 2) | 1];

    if (pp == 0.0f) {
        // Full product exactly 0 -> whole row exactly 0. Plain-store stream.
        f32x4* orow = reinterpret_cast<f32x4*>(out + (size_t)k * N_DIM);
        const f32x4 z = {0.f, 0.f, 0.f, 0.f};
        #pragma unroll
        for (int s = 0; s < 16; ++s)
            orow[half * 1024 + s * 64 + lane] = z;
    } else if (half == 0 && lane == 0) {
        int i = atomicAdd(counter, 1);
        worklist[i] = k;
    }
}

// D4: tailfix -- early-exit on fast path; full general path otherwise.
// grid = TRB x 256. Slow path: full colsum partials (all N), all priors,
// fixup rows (worklist, or ALL rows if flag!=0), Mout rewrite.
__global__ __launch_bounds__(256) void tailfix_kernel(const float* __restrict__ Hxs,
                                                      const int* __restrict__ H,
                                                      const int* __restrict__ x,
                                                      const float* __restrict__ Min,
                                                      const float* __restrict__ dope,
                                                      float* __restrict__ prior_eps,
                                                      float* __restrict__ partial1,
                                                      float* __restrict__ colsum_new,
                                                      const int* __restrict__ flag,
                                                      const int* __restrict__ counter,
                                                      const int* __restrict__ worklist,
                                                      float* __restrict__ out,
                                                      float* __restrict__ Mout,
                                                      unsigned* __restrict__ bar) {
    const int fl = *flag;
    const int cnt = fl ? K_DIM : *counter;
    if (cnt == 0) return;                 // fast path: zeros + optimistic Mout stand

    const int b = blockIdx.x;
    const int t = threadIdx.x;
    const int lane = t & 63;

    // E: full colsum partials (all N cols), 16 rows per block.
    {
        const f32x4* p = reinterpret_cast<const f32x4*>(Hxs + (size_t)b * 16 * N_DIM);
        f32x4 acc[8];
        #pragma unroll
        for (int c = 0; c < 8; ++c) acc[c] = (f32x4){0.f, 0.f, 0.f, 0.f};
        for (int r = 0; r < 16; ++r) {
            #pragma unroll
            for (int c = 0; c < 8; ++c) {
                f32x4 v = p[(size_t)r * (N_DIM / 4) + c * 256 + t];
                acc[c].x += v.x; acc[c].y += v.y; acc[c].z += v.z; acc[c].w += v.w;
            }
        }
        f32x4* pr = reinterpret_cast<f32x4*>(partial1 + (size_t)b * N_DIM);
        #pragma unroll
        for (int c = 0; c < 8; ++c) pr[c * 256 + t] = acc[c];
    }
    grid_barrier(bar, 0, TRB);

    // F: recompute prior_eps for ALL n (valid for any flag state).
    if (b < 32) {
        const int n = b * 256 + t;
        float cs = 0.0f;
        #pragma unroll 8
        for (int i = 0; i < TRB; ++i)
            cs += partial1[(size_t)i * N_DIM + n];
        float m0 = Min[2 * n], m1 = Min[2 * n + 1];
        float m1n = m1 / (m0 + m1);
        float phi = logf(1.0f - m1n) - logf(m1n);
        float prior = dope[n] + phi + cs;
        prior = fminf(fmaxf(prior, -100.0f), 100.0f);
        prior_eps[n] = prior + 1e-4f;
    }
    grid_barrier(bar, 1, TRB);

    // G: fixup rows (full general path; writes ALL columns of each row).
    {
        const int wg = b * 4 + (t >> 6);
        for (int i = wg; i < cnt; i += TRB * 4) {
            const int kk = fl ? i : worklist[i];
            const i32x4* H4  = reinterpret_cast<const i32x4*>(H + (size_t)kk * N_DIM);
            const f32x4* PE4 = reinterpret_cast<const f32x4*>(prior_eps);
            const f32x4* HX4 = reinterpret_cast<const f32x4*>(Hxs + (size_t)kk * N_DIM);

            float lp = 1.0f;
            for (int s = 0; s < 32; ++s) {
                const int idx = s * 64 + lane;
                const i32x4 hh = H4[idx];
                const f32x4 pe = PE4[idx];
                const f32x4 hx = HX4[idx];
                float t0 = fast_tanh_half((hh.x ? pe.x : 0.f) - hx.x);
                float t1 = fast_tanh_half((hh.y ? pe.y : 0.f) - hx.y);
                float t2 = fast_tanh_half((hh.z ? pe.z : 0.f) - hx.z);
                float t3 = fast_tanh_half((hh.w ? pe.w : 0.f) - hx.w);
                t0 = (t0 == 0.f) ? 1.f : t0;
                t1 = (t1 == 0.f) ? 1.f : t1;
                t2 = (t2 == 0.f) ? 1.f : t2;
                t3 = (t3 == 0.f) ? 1.f : t3;
                lp *= (t0 * t1) * (t2 * t3);
            }
            #pragma unroll
            for (int off = 1; off < 64; off <<= 1)
                lp *= __shfl_xor(lp, off);

            const float sgn = 1.0f - 2.0f * (float)x[kk];
            const float P = sgn * lp;

            f32x4* orow = reinterpret_cast<f32x4*>(out + (size_t)kk * N_DIM);
            for (int s = 0; s < 32; ++s) {
                const int idx = s * 64 + lane;
                const i32x4 hh = H4[idx];
                const f32x4 pe = PE4[idx];
                const f32x4 hx = HX4[idx];
                float t0 = fast_tanh_half((hh.x ? pe.x : 0.f) - hx.x);
                float t1 = fast_tanh_half((hh.y ? pe.y : 0.f) - hx.y);
                float t2 = fast_tanh_half((hh.z ? pe.z : 0.f) - hx.z);
                float t3 = fast_tanh_half((hh.w ? pe.w : 0.f) - hx.w);
                f32x4 o;
                o.x = check_msg(t0, P);
                o.y = check_msg(t1, P);
                o.z = check_msg(t2, P);
                o.w = check_msg(t3, P);
                orow[idx] = o;
                const int n0 = idx * 4;
                if (o.x != 0.f) atomicAdd(&colsum_new[n0 + 0], o.x);
                if (o.y != 0.f) atomicAdd(&colsum_new[n0 + 1], o.y);
                if (o.z != 0.f) atomicAdd(&colsum_new[n0 + 2], o.z);
                if (o.w != 0.f) atomicAdd(&colsum_new[n0 + 3], o.w);
            }
        }
    }
    grid_barrier(bar, 2, TRB);

    // H: rewrite Mout with the true colsum_new.
    if (b < 32) {
        const int n = b * 256 + t;
        float z = (1.0f - tanhf((colsum_new[n] + dope[n]) * 0.5f)) * 0.5f;
        float2 m; m.x = 1.0f - z; m.y = z;
        reinterpret_cast<float2*>(Mout)[n] = m;
    }
}

extern "C" void kernel_launch(void* const* d_in, const int* in_sizes, int n_in,
                              void* d_out, int out_size, void* d_ws, size_t ws_size,
                              hipStream_t stream) {
    (void)in_sizes; (void)n_in; (void)out_size; (void)ws_size;
    const float* ps  = (const float*)d_in[0];
    const float* Min = (const float*)d_in[1];
    const float* Hxs = (const float*)d_in[2];
    const int*   x   = (const int*)d_in[3];
    const int*   H   = (const int*)d_in[4];

    float* out = (float*)d_out;
    float* Mout = out;                       // N*2 floats
    float* Hxs_new = out + 2 * N_DIM;        // K*N floats

    unsigned* bar     = (unsigned*)d_ws;                      // 64 uints
    float* partial1   = (float*)d_ws + 64;                    // TRB*N (8 MB, slow path)
    float* prior_eps  = partial1 + (size_t)TRB * N_DIM;       // N
    float* dope       = prior_eps + N_DIM;                    // N
    float* Tprod      = dope + N_DIM;                         // PREFIX
    float* colsum_new = Tprod + PREFIX;                       // N
    int*   flag       = (int*)(colsum_new + N_DIM);
    int*   counter    = flag + 64;
    int*   worklist   = counter + 64;                         // K ints
    int*   nzp        = worklist + K_DIM;                     // PCB ints

    nzscan_kernel<<<PCB, 256, 0, stream>>>(Hxs, nzp);

    prep_kernel<<<N_DIM / 256, 256, 0, stream>>>(ps, Min, nzp,
                                                 prior_eps, dope, Tprod,
                                                 colsum_new, Mout, flag,
                                                 counter, bar);

    mainfill_kernel<<<MFB, 256, 0, stream>>>(H, Tprod, flag, Hxs_new,
                                             counter, worklist);

    tailfix_kernel<<<TRB, 256, 0, stream>>>(Hxs, H, x, Min, dope, prior_eps,
                                            partial1, colsum_new, flag, counter,
                                            worklist, Hxs_new, Mout, bar);
}

// Round 18
// 31.523 us; speedup vs baseline: 5.8173x; 1.0603x over previous
//
#include <hip/hip_runtime.h>

#define K_DIM 4096
#define N_DIM 8192
#define PREFIX 512              // prefix columns for the underflow test
#define MFB (K_DIM / 2)         // mainfill blocks (2048; 2 rows each)
#define TRB 256                 // tailfix blocks (slow path; 1/CU co-resident)

typedef float f32x4 __attribute__((ext_vector_type(4)));
typedef int   i32x4 __attribute__((ext_vector_type(4)));
typedef unsigned int u32x4 __attribute__((ext_vector_type(4)));

// ws layout:
// bar[64] (uint; zeroed by prep; used only on slow path)
// partial1 [TRB*N]  (8 MB, slow path only)
// prior_eps[N], dope[N], Tprod[PREFIX], colsum_new[N]
// nzflag[64], counter[64], worklist[K]  (ints)

__device__ __forceinline__ float fast_tanh_half(float h) {
    // tanh(h/2) = 1 - 2/(e^h + 1)
    float e = __expf(h);
    float r = __builtin_amdgcn_rcpf(e + 1.0f);
    return __builtin_fmaf(-2.0f, r, 1.0f);
}

// clip(2*atanh(P/t), -1, 1) for t != 0, else 0.  2*atanh(P/t)=ln((t+P)/(t-P))
__device__ __forceinline__ float check_msg(float t, float P) {
    float q = (t + P) * __builtin_amdgcn_rcpf(t - P);
    float m = 0.69314718055994531f * __log2f(q);
    m = fminf(fmaxf(m, -1.0f), 1.0f);
    return (t == 0.0f) ? 0.0f : m;
}

// Grid barrier for the SLOW PATH ONLY (never executed on the fast path).
// TRB=256 blocks = 1 block/CU -> co-resident. Correctness-grade, not fast.
__device__ __forceinline__ void grid_barrier(unsigned* bar, int slot, int nblk) {
    __syncthreads();
    if (threadIdx.x == 0) {
        unsigned* cnt = bar + 2 * slot;
        unsigned* gen = bar + 2 * slot + 1;
        __threadfence();
        unsigned g = __hip_atomic_load(gen, __ATOMIC_ACQUIRE, __HIP_MEMORY_SCOPE_AGENT);
        if (__hip_atomic_fetch_add(cnt, 1u, __ATOMIC_ACQ_REL, __HIP_MEMORY_SCOPE_AGENT) == (unsigned)(nblk - 1)) {
            __hip_atomic_fetch_add(gen, 1u, __ATOMIC_RELEASE, __HIP_MEMORY_SCOPE_AGENT);
        } else {
            while (__hip_atomic_load(gen, __ATOMIC_ACQUIRE, __HIP_MEMORY_SCOPE_AGENT) == g)
                __builtin_amdgcn_s_sleep(32);
        }
        __threadfence();
    }
    __syncthreads();
}

// D1: prep. grid = 32 x 256 (thread per column n). No input dependencies
// besides ps/Min. dope all N; colsum_new=0; optimistic Mout=f(dope) (exact on
// fast path); n<PREFIX: prior/Tprod with colsum==0 (valid iff Hxs prefix is
// all-zero; only trusted then). Block 0: nzflag=0, counter=0, bar=0.
__global__ __launch_bounds__(256) void prep_kernel(const float* __restrict__ ps,
                                                   const float* __restrict__ Min,
                                                   float* __restrict__ prior_eps,
                                                   float* __restrict__ dope_out,
                                                   float* __restrict__ Tprod,
                                                   float* __restrict__ colsum_new,
                                                   float* __restrict__ Mout,
                                                   int* __restrict__ nzflag,
                                                   int* __restrict__ counter,
                                                   unsigned* __restrict__ bar) {
    const int t = threadIdx.x;
    const int n = blockIdx.x * 256 + t;

    float p0 = ps[2 * n], p1 = ps[2 * n + 1];
    float p1n = p1 / (p0 + p1);
    float dp = logf(1.0f - p1n) - logf(p1n);
    dope_out[n] = dp;
    colsum_new[n] = 0.0f;

    // Optimistic output beliefs (colsum_new == 0); tailfix rewrites on slow path.
    {
        float z = (1.0f - tanhf(dp * 0.5f)) * 0.5f;
        float2 m; m.x = 1.0f - z; m.y = z;
        reinterpret_cast<float2*>(Mout)[n] = m;
    }

    if (blockIdx.x == 0 && t < 64) {
        if (t == 0) { nzflag[0] = 0; counter[0] = 0; }
        bar[t] = 0u;
    }

    if (n < PREFIX) {
        float m0 = Min[2 * n], m1 = Min[2 * n + 1];
        float m1n = m1 / (m0 + m1);
        float phi = logf(1.0f - m1n) - logf(m1n);
        float prior = dp + phi;
        prior = fminf(fmaxf(prior, -100.0f), 100.0f);
        float pe = prior + 1e-4f;
        prior_eps[n] = pe;
        float T = tanhf(pe * 0.5f);
        Tprod[n] = (T == 0.0f) ? 1.0f : T;
    }
}

// D2: mainfill -- fused local-nzscan + prefix-test + zero-fill.
// grid = MFB x 256 (8 blocks/CU, full occupancy). Block b: rows 2b, 2b+1;
// 2 waves/row. Per wave: 1 Hxs-f32x4 (local nz check), 1 H-int4, 1 Tprod-f32x4
// (256 prefix cols), product, butterfly; block combine via LDS + 2 barriers.
// Local Hxs clean AND pp==0 (|t|<=1 monotone underflow, the common case)
// -> plain-store the 16KB half-row of zeros. Clean but pp!=0 -> worklist.
// Local Hxs nonzero -> set global nzflag (tailfix recomputes ALL rows,
// overwriting any zeros streamed by other blocks with then-invalid Tprod).
__global__ __launch_bounds__(256, 8) void mainfill_kernel(const float* __restrict__ Hxs,
                                                          const int* __restrict__ H,
                                                          const float* __restrict__ Tprod,
                                                          float* __restrict__ out,
                                                          int* __restrict__ counter,
                                                          int* __restrict__ worklist,
                                                          int* __restrict__ nzflag) {
    const int t = threadIdx.x;
    const int w = t >> 6;                 // 0..3
    const int lane = t & 63;
    const int half = w & 1;
    const int k = blockIdx.x * 2 + (w >> 1);

    const i32x4* H4  = reinterpret_cast<const i32x4*>(H + (size_t)k * N_DIM);
    const f32x4* HX4 = reinterpret_cast<const f32x4*>(Hxs + (size_t)k * N_DIM);
    const f32x4* TP4 = reinterpret_cast<const f32x4*>(Tprod);

    const int idx = half * 64 + lane;     // f32x4/int4 idx in [0,128) = cols [0,512)

    // ---- local Hxs-prefix nz check + half-row prefix product ----
    const f32x4 hx = __builtin_nontemporal_load(&HX4[idx]);
    u32x4 u;
    __builtin_memcpy(&u, &hx, 16);
    const unsigned nzbits = (u.x | u.y | u.z | u.w);

    const i32x4 hh = H4[idx];
    const f32x4 tv = TP4[idx];
    float f0 = hh.x ? tv.x : 1.f;
    float f1 = hh.y ? tv.y : 1.f;
    float f2 = hh.z ? tv.z : 1.f;
    float f3 = hh.w ? tv.w : 1.f;
    float hp = (f0 * f1) * (f2 * f3);
    #pragma unroll
    for (int off = 1; off < 64; off <<= 1)
        hp *= __shfl_xor(hp, off);

    __shared__ float sh[4];
    __shared__ int snz;
    if (t == 0) snz = 0;
    __syncthreads();
    if (lane == 0) sh[w] = hp;
    if (__any(nzbits != 0u ? 1 : 0)) {
        if (lane == 0) atomicOr(&snz, 1);     // LDS atomic only
    }
    __syncthreads();
    const float pp = sh[w & 2] * sh[(w & 2) | 1];
    const int blocknz = snz;

    if (blocknz == 0) {
        if (pp == 0.0f) {
            // Full product exactly 0 -> whole row exactly 0. Plain-store stream.
            f32x4* orow = reinterpret_cast<f32x4*>(out + (size_t)k * N_DIM);
            const f32x4 z = {0.f, 0.f, 0.f, 0.f};
            #pragma unroll
            for (int s = 0; s < 16; ++s)
                orow[half * 1024 + s * 64 + lane] = z;
        } else if (half == 0 && lane == 0) {
            int i = atomicAdd(counter, 1);
            worklist[i] = k;
        }
    } else if (t == 0) {
        atomicOr(nzflag, 1);                  // rare: poisons fast path globally
    }
}

// D3: tailfix -- early-exit on fast path; full general path otherwise.
// grid = TRB x 256. Slow path: full colsum partials (all N), all priors,
// fixup rows (worklist, or ALL rows if nzflag!=0), Mout rewrite.
__global__ __launch_bounds__(256) void tailfix_kernel(const float* __restrict__ Hxs,
                                                      const int* __restrict__ H,
                                                      const int* __restrict__ x,
                                                      const float* __restrict__ Min,
                                                      const float* __restrict__ dope,
                                                      float* __restrict__ prior_eps,
                                                      float* __restrict__ partial1,
                                                      float* __restrict__ colsum_new,
                                                      const int* __restrict__ nzflag,
                                                      const int* __restrict__ counter,
                                                      const int* __restrict__ worklist,
                                                      float* __restrict__ out,
                                                      float* __restrict__ Mout,
                                                      unsigned* __restrict__ bar) {
    const int fl = *nzflag;
    const int cnt = fl ? K_DIM : *counter;
    if (cnt == 0) return;                 // fast path: zeros + optimistic Mout stand

    const int b = blockIdx.x;
    const int t = threadIdx.x;
    const int lane = t & 63;

    // E: full colsum partials (all N cols), 16 rows per block.
    {
        const f32x4* p = reinterpret_cast<const f32x4*>(Hxs + (size_t)b * 16 * N_DIM);
        f32x4 acc[8];
        #pragma unroll
        for (int c = 0; c < 8; ++c) acc[c] = (f32x4){0.f, 0.f, 0.f, 0.f};
        for (int r = 0; r < 16; ++r) {
            #pragma unroll
            for (int c = 0; c < 8; ++c) {
                f32x4 v = p[(size_t)r * (N_DIM / 4) + c * 256 + t];
                acc[c].x += v.x; acc[c].y += v.y; acc[c].z += v.z; acc[c].w += v.w;
            }
        }
        f32x4* pr = reinterpret_cast<f32x4*>(partial1 + (size_t)b * N_DIM);
        #pragma unroll
        for (int c = 0; c < 8; ++c) pr[c * 256 + t] = acc[c];
    }
    grid_barrier(bar, 0, TRB);

    // F: recompute prior_eps for ALL n (valid for any nzflag state).
    if (b < 32) {
        const int n = b * 256 + t;
        float cs = 0.0f;
        #pragma unroll 8
        for (int i = 0; i < TRB; ++i)
            cs += partial1[(size_t)i * N_DIM + n];
        float m0 = Min[2 * n], m1 = Min[2 * n + 1];
        float m1n = m1 / (m0 + m1);
        float phi = logf(1.0f - m1n) - logf(m1n);
        float prior = dope[n] + phi + cs;
        prior = fminf(fmaxf(prior, -100.0f), 100.0f);
        prior_eps[n] = prior + 1e-4f;
    }
    grid_barrier(bar, 1, TRB);

    // G: fixup rows (full general path; writes ALL columns of each row).
    {
        const int wg = b * 4 + (t >> 6);
        for (int i = wg; i < cnt; i += TRB * 4) {
            const int kk = fl ? i : worklist[i];
            const i32x4* H4  = reinterpret_cast<const i32x4*>(H + (size_t)kk * N_DIM);
            const f32x4* PE4 = reinterpret_cast<const f32x4*>(prior_eps);
            const f32x4* HX4 = reinterpret_cast<const f32x4*>(Hxs + (size_t)kk * N_DIM);

            float lp = 1.0f;
            for (int s = 0; s < 32; ++s) {
                const int idx = s * 64 + lane;
                const i32x4 hh = H4[idx];
                const f32x4 pe = PE4[idx];
                const f32x4 hx = HX4[idx];
                float t0 = fast_tanh_half((hh.x ? pe.x : 0.f) - hx.x);
                float t1 = fast_tanh_half((hh.y ? pe.y : 0.f) - hx.y);
                float t2 = fast_tanh_half((hh.z ? pe.z : 0.f) - hx.z);
                float t3 = fast_tanh_half((hh.w ? pe.w : 0.f) - hx.w);
                t0 = (t0 == 0.f) ? 1.f : t0;
                t1 = (t1 == 0.f) ? 1.f : t1;
                t2 = (t2 == 0.f) ? 1.f : t2;
                t3 = (t3 == 0.f) ? 1.f : t3;
                lp *= (t0 * t1) * (t2 * t3);
            }
            #pragma unroll
            for (int off = 1; off < 64; off <<= 1)
                lp *= __shfl_xor(lp, off);

            const float sgn = 1.0f - 2.0f * (float)x[kk];
            const float P = sgn * lp;

            f32x4* orow = reinterpret_cast<f32x4*>(out + (size_t)kk * N_DIM);
            for (int s = 0; s < 32; ++s) {
                const int idx = s * 64 + lane;
                const i32x4 hh = H4[idx];
                const f32x4 pe = PE4[idx];
                const f32x4 hx = HX4[idx];
                float t0 = fast_tanh_half((hh.x ? pe.x : 0.f) - hx.x);
                float t1 = fast_tanh_half((hh.y ? pe.y : 0.f) - hx.y);
                float t2 = fast_tanh_half((hh.z ? pe.z : 0.f) - hx.z);
                float t3 = fast_tanh_half((hh.w ? pe.w : 0.f) - hx.w);
                f32x4 o;
                o.x = check_msg(t0, P);
                o.y = check_msg(t1, P);
                o.z = check_msg(t2, P);
                o.w = check_msg(t3, P);
                orow[idx] = o;
                const int n0 = idx * 4;
                if (o.x != 0.f) atomicAdd(&colsum_new[n0 + 0], o.x);
                if (o.y != 0.f) atomicAdd(&colsum_new[n0 + 1], o.y);
                if (o.z != 0.f) atomicAdd(&colsum_new[n0 + 2], o.z);
                if (o.w != 0.f) atomicAdd(&colsum_new[n0 + 3], o.w);
            }
        }
    }
    grid_barrier(bar, 2, TRB);

    // H: rewrite Mout with the true colsum_new.
    if (b < 32) {
        const int n = b * 256 + t;
        float z = (1.0f - tanhf((colsum_new[n] + dope[n]) * 0.5f)) * 0.5f;
        float2 m; m.x = 1.0f - z; m.y = z;
        reinterpret_cast<float2*>(Mout)[n] = m;
    }
}

extern "C" void kernel_launch(void* const* d_in, const int* in_sizes, int n_in,
                              void* d_out, int out_size, void* d_ws, size_t ws_size,
                              hipStream_t stream) {
    (void)in_sizes; (void)n_in; (void)out_size; (void)ws_size;
    const float* ps  = (const float*)d_in[0];
    const float* Min = (const float*)d_in[1];
    const float* Hxs = (const float*)d_in[2];
    const int*   x   = (const int*)d_in[3];
    const int*   H   = (const int*)d_in[4];

    float* out = (float*)d_out;
    float* Mout = out;                       // N*2 floats
    float* Hxs_new = out + 2 * N_DIM;        // K*N floats

    unsigned* bar     = (unsigned*)d_ws;                      // 64 uints
    float* partial1   = (float*)d_ws + 64;                    // TRB*N (8 MB, slow path)
    float* prior_eps  = partial1 + (size_t)TRB * N_DIM;       // N
    float* dope       = prior_eps + N_DIM;                    // N
    float* Tprod      = dope + N_DIM;                         // PREFIX
    float* colsum_new = Tprod + PREFIX;                       // N
    int*   nzflag     = (int*)(colsum_new + N_DIM);
    int*   counter    = nzflag + 64;
    int*   worklist   = counter + 64;                         // K ints

    prep_kernel<<<N_DIM / 256, 256, 0, stream>>>(ps, Min, prior_eps, dope,
                                                 Tprod, colsum_new, Mout,
                                                 nzflag, counter, bar);

    mainfill_kernel<<<MFB, 256, 0, stream>>>(Hxs, H, Tprod, Hxs_new,
                                             counter, worklist, nzflag);

    tailfix_kernel<<<TRB, 256, 0, stream>>>(Hxs, H, x, Min, dope, prior_eps,
                                            partial1, colsum_new, nzflag,
                                            counter, worklist, Hxs_new, Mout,
                                            bar);
}

// Round 19
// 29.438 us; speedup vs baseline: 6.2292x; 1.0708x over previous
//
#include <hip/hip_runtime.h>

#define K_DIM 4096
#define N_DIM 8192
#define PREFIX 512              // prefix columns for the underflow test
#define MFB (K_DIM / 2)         // mainfill blocks (2048; 2 rows each)

typedef float f32x4 __attribute__((ext_vector_type(4)));
typedef int   i32x4 __attribute__((ext_vector_type(4)));
typedef unsigned int u32x4 __attribute__((ext_vector_type(4)));

// ws layout: prior_eps[N], colsum_new[N] (slow path only), rowstat[K] ints.
// rowstat is fully rewritten by mainfill every launch -> no pre-zeroing, no
// cross-launch state, deterministic.

__device__ __forceinline__ float fast_tanh_half(float h) {
    // tanh(h/2) = 1 - 2/(e^h + 1)
    float e = __expf(h);
    float r = __builtin_amdgcn_rcpf(e + 1.0f);
    return __builtin_fmaf(-2.0f, r, 1.0f);
}

// clip(2*atanh(P/t), -1, 1) for t != 0, else 0.  2*atanh(P/t)=ln((t+P)/(t-P))
__device__ __forceinline__ float check_msg(float t, float P) {
    float q = (t + P) * __builtin_amdgcn_rcpf(t - P);
    float m = 0.69314718055994531f * __log2f(q);
    m = fminf(fmaxf(m, -1.0f), 1.0f);
    return (t == 0.0f) ? 0.0f : m;
}

// D1: mainfill -- self-contained fast path. grid = MFB x 256 (8 blocks/CU).
// Block b: rows 2b, 2b+1; 2 waves/row. Per thread: compute its own 4 Tprod
// values from ps/Min (fast math -- feeds only the underflow test, margin
// ~2^-300), check its Hxs-prefix f32x4 for nonzeros, load H-int4, product,
// butterfly; block combine via LDS. Clean block + pp==0 (|t|<=1 monotone
// underflow, the common case) -> plain-store 16KB half-row of zeros.
// rowstat[k] = 2 (dirty Hxs), 1 (pp!=0), 0 (zeroed) -- written every launch.
// Blocks 0-31 additionally write the optimistic Mout (exact on fast path).
__global__ __launch_bounds__(256, 8) void mainfill_kernel(const float* __restrict__ ps,
                                                          const float* __restrict__ Min,
                                                          const float* __restrict__ Hxs,
                                                          const int* __restrict__ H,
                                                          float* __restrict__ out,
                                                          float* __restrict__ Mout,
                                                          int* __restrict__ rowstat) {
    const int t = threadIdx.x;
    const int w = t >> 6;                 // 0..3
    const int lane = t & 63;
    const int half = w & 1;
    const int k = blockIdx.x * 2 + (w >> 1);

    const int idx = half * 64 + lane;     // f32x4/int4 idx in [0,128) = cols [0,512)

    // ---- per-thread Tprod for cols 4idx..4idx+3 (colsum==0 assumption;
    //      only trusted when no block reports dirty Hxs) ----
    const f32x4* PS4 = reinterpret_cast<const f32x4*>(ps);
    const f32x4* MN4 = reinterpret_cast<const f32x4*>(Min);
    const f32x4 psa = PS4[2 * idx], psb = PS4[2 * idx + 1];
    const f32x4 mna = MN4[2 * idx], mnb = MN4[2 * idx + 1];
    float tp[4];
    {
        const float p0[4] = {psa.x, psa.z, psb.x, psb.z};
        const float p1[4] = {psa.y, psa.w, psb.y, psb.w};
        const float m0[4] = {mna.x, mna.z, mnb.x, mnb.z};
        const float m1[4] = {mna.y, mna.w, mnb.y, mnb.w};
        #pragma unroll
        for (int j = 0; j < 4; ++j) {
            // dope+phi = log(p0/p1) + log(m0/m1) = log(p0*m0/(p1*m1))
            float pe = __logf((p0[j] * m0[j]) / (p1[j] * m1[j]));
            pe = fminf(fmaxf(pe, -100.0f), 100.0f) + 1e-4f;
            float T = fast_tanh_half(pe);
            tp[j] = (T == 0.0f) ? 1.0f : T;
        }
    }

    // ---- local Hxs-prefix nz check + half-row prefix product ----
    const i32x4* H4  = reinterpret_cast<const i32x4*>(H + (size_t)k * N_DIM);
    const f32x4* HX4 = reinterpret_cast<const f32x4*>(Hxs + (size_t)k * N_DIM);

    const f32x4 hx = __builtin_nontemporal_load(&HX4[idx]);
    u32x4 u;
    __builtin_memcpy(&u, &hx, 16);
    const unsigned nzbits = (u.x | u.y | u.z | u.w);

    const i32x4 hh = H4[idx];
    float f0 = hh.x ? tp[0] : 1.f;
    float f1 = hh.y ? tp[1] : 1.f;
    float f2 = hh.z ? tp[2] : 1.f;
    float f3 = hh.w ? tp[3] : 1.f;
    float hp = (f0 * f1) * (f2 * f3);
    #pragma unroll
    for (int off = 1; off < 64; off <<= 1)
        hp *= __shfl_xor(hp, off);

    __shared__ float sh[4];
    __shared__ int snz;
    if (t == 0) snz = 0;
    __syncthreads();
    if (lane == 0) sh[w] = hp;
    if (__any(nzbits != 0u ? 1 : 0)) {
        if (lane == 0) atomicOr(&snz, 1);     // LDS atomic only
    }
    __syncthreads();
    const float pp = sh[w & 2] * sh[(w & 2) | 1];
    const int blocknz = snz;

    if (blocknz == 0 && pp == 0.0f) {
        // Full product exactly 0 -> whole row exactly 0 (independent of the
        // Hxs tail: P==0 makes every check_msg 0). Plain-store stream.
        f32x4* orow = reinterpret_cast<f32x4*>(out + (size_t)k * N_DIM);
        const f32x4 z = {0.f, 0.f, 0.f, 0.f};
        #pragma unroll
        for (int s = 0; s < 16; ++s)
            orow[half * 1024 + s * 64 + lane] = z;
    }
    if (half == 0 && lane == 0)
        rowstat[k] = blocknz ? 2 : (pp != 0.0f ? 1 : 0);

    // ---- optimistic Mout (colsum_new == 0), reference-exact math ----
    if (blockIdx.x < 32) {
        const int n = blockIdx.x * 256 + t;
        float p0 = ps[2 * n], p1 = ps[2 * n + 1];
        float p1n = p1 / (p0 + p1);
        float dp = logf(1.0f - p1n) - logf(p1n);
        float z = (1.0f - tanhf(dp * 0.5f)) * 0.5f;
        float2 m; m.x = 1.0f - z; m.y = z;
        reinterpret_cast<float2*>(Mout)[n] = m;
    }
}

// D2: tailfix -- grid = 1 block. Scan rowstat (16 KB); all-zero -> return
// (fast path). Otherwise single-block full recompute from scratch:
// true colsums -> priors -> rows (all rows if any stat==2, else stat==1
// rows) -> Mout rewrite. Correctness-grade; never runs on the fast path.
__global__ __launch_bounds__(256) void tailfix_kernel(const float* __restrict__ ps,
                                                      const float* __restrict__ Min,
                                                      const float* __restrict__ Hxs,
                                                      const int* __restrict__ H,
                                                      const int* __restrict__ x,
                                                      const int* __restrict__ rowstat,
                                                      float* __restrict__ prior_eps,
                                                      float* __restrict__ colsum_new,
                                                      float* __restrict__ out,
                                                      float* __restrict__ Mout) {
    const int t = threadIdx.x;
    const int lane = t & 63;

    int any = 0, dirty = 0;
    for (int i = t; i < K_DIM; i += 256) {
        int s = rowstat[i];
        any |= (s != 0);
        dirty |= (s == 2);
    }
    __shared__ int sAny, sDirty;
    if (t == 0) { sAny = 0; sDirty = 0; }
    __syncthreads();
    if (__any(any ? 1 : 0))   { if (lane == 0) atomicOr(&sAny, 1); }
    if (__any(dirty ? 1 : 0)) { if (lane == 0) atomicOr(&sDirty, 1); }
    __syncthreads();
    if (sAny == 0) return;                // fast path: zeros + optimistic Mout stand

    const int fl = sDirty;

    // 1) true colsum over ALL rows -> prior_eps; zero colsum_new.
    for (int n = t; n < N_DIM; n += 256) {
        float cs = 0.0f;
        for (int r = 0; r < K_DIM; ++r)
            cs += Hxs[(size_t)r * N_DIM + n];
        float p0 = ps[2 * n], p1 = ps[2 * n + 1];
        float p1n = p1 / (p0 + p1);
        float dp = logf(1.0f - p1n) - logf(p1n);
        float m0 = Min[2 * n], m1 = Min[2 * n + 1];
        float m1n = m1 / (m0 + m1);
        float phi = logf(1.0f - m1n) - logf(m1n);
        float prior = dp + phi + cs;
        prior = fminf(fmaxf(prior, -100.0f), 100.0f);
        prior_eps[n] = prior + 1e-4f;
        colsum_new[n] = 0.0f;
    }
    __syncthreads();

    // 2) rows: all rows if fl (zero-streams used invalid Tprod), else stat==1.
    {
        const int wv = t >> 6;
        for (int r = wv; r < K_DIM; r += 4) {
            if (!fl && rowstat[r] == 0) continue;
            const i32x4* H4  = reinterpret_cast<const i32x4*>(H + (size_t)r * N_DIM);
            const f32x4* PE4 = reinterpret_cast<const f32x4*>(prior_eps);
            const f32x4* HX4 = reinterpret_cast<const f32x4*>(Hxs + (size_t)r * N_DIM);

            float lp = 1.0f;
            for (int s = 0; s < 32; ++s) {
                const int idx = s * 64 + lane;
                const i32x4 hh = H4[idx];
                const f32x4 pe = PE4[idx];
                const f32x4 hx = HX4[idx];
                float t0 = fast_tanh_half((hh.x ? pe.x : 0.f) - hx.x);
                float t1 = fast_tanh_half((hh.y ? pe.y : 0.f) - hx.y);
                float t2 = fast_tanh_half((hh.z ? pe.z : 0.f) - hx.z);
                float t3 = fast_tanh_half((hh.w ? pe.w : 0.f) - hx.w);
                t0 = (t0 == 0.f) ? 1.f : t0;
                t1 = (t1 == 0.f) ? 1.f : t1;
                t2 = (t2 == 0.f) ? 1.f : t2;
                t3 = (t3 == 0.f) ? 1.f : t3;
                lp *= (t0 * t1) * (t2 * t3);
            }
            #pragma unroll
            for (int off = 1; off < 64; off <<= 1)
                lp *= __shfl_xor(lp, off);

            const float sgn = 1.0f - 2.0f * (float)x[r];
            const float P = sgn * lp;

            f32x4* orow = reinterpret_cast<f32x4*>(out + (size_t)r * N_DIM);
            for (int s = 0; s < 32; ++s) {
                const int idx = s * 64 + lane;
                const i32x4 hh = H4[idx];
                const f32x4 pe = PE4[idx];
                const f32x4 hx = HX4[idx];
                float t0 = fast_tanh_half((hh.x ? pe.x : 0.f) - hx.x);
                float t1 = fast_tanh_half((hh.y ? pe.y : 0.f) - hx.y);
                float t2 = fast_tanh_half((hh.z ? pe.z : 0.f) - hx.z);
                float t3 = fast_tanh_half((hh.w ? pe.w : 0.f) - hx.w);
                f32x4 o;
                o.x = check_msg(t0, P);
                o.y = check_msg(t1, P);
                o.z = check_msg(t2, P);
                o.w = check_msg(t3, P);
                orow[idx] = o;
                const int n0 = idx * 4;
                if (o.x != 0.f) atomicAdd(&colsum_new[n0 + 0], o.x);
                if (o.y != 0.f) atomicAdd(&colsum_new[n0 + 1], o.y);
                if (o.z != 0.f) atomicAdd(&colsum_new[n0 + 2], o.z);
                if (o.w != 0.f) atomicAdd(&colsum_new[n0 + 3], o.w);
            }
        }
    }
    __syncthreads();

    // 3) Mout rewrite with the true colsum_new.
    for (int n = t; n < N_DIM; n += 256) {
        float p0 = ps[2 * n], p1 = ps[2 * n + 1];
        float p1n = p1 / (p0 + p1);
        float dp = logf(1.0f - p1n) - logf(p1n);
        float z = (1.0f - tanhf((colsum_new[n] + dp) * 0.5f)) * 0.5f;
        Mout[2 * n]     = 1.0f - z;
        Mout[2 * n + 1] = z;
    }
}

extern "C" void kernel_launch(void* const* d_in, const int* in_sizes, int n_in,
                              void* d_out, int out_size, void* d_ws, size_t ws_size,
                              hipStream_t stream) {
    (void)in_sizes; (void)n_in; (void)out_size; (void)ws_size;
    const float* ps  = (const float*)d_in[0];
    const float* Min = (const float*)d_in[1];
    const float* Hxs = (const float*)d_in[2];
    const int*   x   = (const int*)d_in[3];
    const int*   H   = (const int*)d_in[4];

    float* out = (float*)d_out;
    float* Mout = out;                       // N*2 floats
    float* Hxs_new = out + 2 * N_DIM;        // K*N floats

    float* prior_eps  = (float*)d_ws;                         // N
    float* colsum_new = prior_eps + N_DIM;                    // N
    int*   rowstat    = (int*)(colsum_new + N_DIM);           // K ints

    mainfill_kernel<<<MFB, 256, 0, stream>>>(ps, Min, Hxs, H, Hxs_new,
                                             Mout, rowstat);

    tailfix_kernel<<<1, 256, 0, stream>>>(ps, Min, Hxs, H, x, rowstat,
                                          prior_eps, colsum_new,
                                          Hxs_new, Mout);
}